// Round 1
// baseline (3057.953 us; speedup 1.0000x reference)
//
#include <hip/hip_runtime.h>
#include <hip/hip_bf16.h>

#define NN 50000
#define NE 800000
#define DH 128

// ---------- edge dtype detection (int32 vs int64) ----------
__global__ void detect_mode_kernel(const void* ei, int* mode) {
    if (threadIdx.x == 0 && blockIdx.x == 0) {
        const long long* p = (const long long*)ei;
        int ok64 = 1;
        for (int i = 0; i < 128; ++i) {
            long long v = p[i];
            if (v < 0 || v >= NN) { ok64 = 0; break; }
        }
        *mode = ok64;
    }
}

__device__ __forceinline__ int edge_at(const void* ei, int mode, int idx) {
    if (mode) return (int)((const long long*)ei)[idx];
    return ((const int*)ei)[idx];
}

// ---------- degree / dinv ----------
__global__ void deg_kernel(const void* ei, const int* mode_p, float* deg) {
    int e = blockIdx.x * blockDim.x + threadIdx.x;
    if (e >= NE) return;
    int mode = *mode_p;
    int d = edge_at(ei, mode, NE + e);
    atomicAdd(&deg[d], 1.0f);
}

__global__ void dinv_kernel(const float* __restrict__ deg, float* __restrict__ dinv) {
    int i = blockIdx.x * blockDim.x + threadIdx.x;
    if (i >= NN) return;
    dinv[i] = rsqrtf(deg[i] + 1.0f);   // +1 = self loop; always > 0
}

// ---------- edge scatter: h0[dst] += xw[src] * dinv[src]*dinv[dst] ----------
__global__ void scatter_kernel(const void* ei, const int* mode_p,
                               const float* __restrict__ xw,
                               const float* __restrict__ dinv,
                               float* __restrict__ h0) {
    int t = blockIdx.x * blockDim.x + threadIdx.x;   // 32 threads per edge
    int e = t >> 5;
    int r = t & 31;
    if (e >= NE) return;
    int mode = *mode_p;
    int s = edge_at(ei, mode, e);
    int d = edge_at(ei, mode, NE + e);
    float norm = dinv[s] * dinv[d];
    const float4 v = *(const float4*)(xw + (size_t)s * DH + r * 4);
    float* o = h0 + (size_t)d * DH + r * 4;
    atomicAdd(o + 0, v.x * norm);
    atomicAdd(o + 1, v.y * norm);
    atomicAdd(o + 2, v.z * norm);
    atomicAdd(o + 3, v.w * norm);
}

// ---------- finalize: h0 = relu(h0 + xw*dinv^2 + b) (self loop + bias + relu) ----------
__global__ void finalize_h0(const float* __restrict__ xw, const float* __restrict__ dinv,
                            const float* __restrict__ bias, float* __restrict__ h0) {
    int i = blockIdx.x * blockDim.x + threadIdx.x;
    if (i >= NN * DH) return;
    int node = i >> 7;
    int d = i & 127;
    float di = dinv[node];
    float v = h0[i] + xw[i] * di * di + bias[d];
    h0[i] = v > 0.f ? v : 0.f;
}

// ---------- tiled fp32 GEMM: C = [relu](A @ B [+ bias]) ----------
// 64x64 tile, 256 threads, 4x4 per thread, K-step 16
template <bool RELU, bool BIAS>
__global__ __launch_bounds__(256)
void gemm_tiled(const float* __restrict__ A, const float* __restrict__ B,
                const float* __restrict__ bias, float* __restrict__ C,
                int M, int N, int K) {
    __shared__ float As[16][65];
    __shared__ float Bs[16][65];
    int tid = threadIdx.x;
    int tx = tid & 15, ty = tid >> 4;
    int row0 = blockIdx.y * 64, col0 = blockIdx.x * 64;
    float acc[4][4] = {};
    for (int k0 = 0; k0 < K; k0 += 16) {
#pragma unroll
        for (int i = 0; i < 4; ++i) {
            int e = tid + i * 256;
            int m = e >> 4, kk = e & 15;
            int row = row0 + m, k = k0 + kk;
            As[kk][m] = (row < M && k < K) ? A[(size_t)row * K + k] : 0.f;
        }
#pragma unroll
        for (int i = 0; i < 4; ++i) {
            int e = tid + i * 256;
            int kk = e >> 6, n = e & 63;
            int col = col0 + n, k = k0 + kk;
            Bs[kk][n] = (col < N && k < K) ? B[(size_t)k * N + col] : 0.f;
        }
        __syncthreads();
#pragma unroll
        for (int kk = 0; kk < 16; ++kk) {
            float a[4], b[4];
#pragma unroll
            for (int i = 0; i < 4; ++i) a[i] = As[kk][ty * 4 + i];
#pragma unroll
            for (int j = 0; j < 4; ++j) b[j] = Bs[kk][tx * 4 + j];
#pragma unroll
            for (int i = 0; i < 4; ++i)
#pragma unroll
                for (int j = 0; j < 4; ++j) acc[i][j] += a[i] * b[j];
        }
        __syncthreads();
    }
#pragma unroll
    for (int i = 0; i < 4; ++i) {
        int row = row0 + ty * 4 + i;
        if (row >= M) continue;
#pragma unroll
        for (int j = 0; j < 4; ++j) {
            int col = col0 + tx * 4 + j;
            if (col >= N) continue;
            float v = acc[i][j];
            if (BIAS) v += bias[col];
            if (RELU) v = v > 0.f ? v : 0.f;
            C[(size_t)row * N + col] = v;
        }
    }
}

// ---------- final layer: out[i] = dot(H[i,:500], Wo) + bo ----------
__global__ void final_gemv(const float* __restrict__ H, const float* __restrict__ Wo,
                           const float* __restrict__ bo, float* __restrict__ out) {
    int wave = threadIdx.x >> 6;
    int lane = threadIdx.x & 63;
    int row = blockIdx.x * 4 + wave;
    if (row >= NN) return;
    const float* h = H + (size_t)row * 500;
    float s = 0.f;
    for (int k = lane; k < 500; k += 64) s += h[k] * Wo[k];
#pragma unroll
    for (int off = 32; off > 0; off >>= 1) s += __shfl_down(s, off, 64);
    if (lane == 0) out[row] = s + bo[0];
}

extern "C" void kernel_launch(void* const* d_in, const int* in_sizes, int n_in,
                              void* d_out, int out_size, void* d_ws, size_t ws_size,
                              hipStream_t stream) {
    const float* x      = (const float*)d_in[0];
    const void*  ei     = d_in[1];
    const float* conv_W = (const float*)d_in[2];
    const float* conv_b = (const float*)d_in[3];
    const float* W1 = (const float*)d_in[4];
    const float* b1 = (const float*)d_in[5];
    const float* W2 = (const float*)d_in[6];
    const float* b2 = (const float*)d_in[7];
    const float* W3 = (const float*)d_in[8];
    const float* b3 = (const float*)d_in[9];
    const float* Wo = (const float*)d_in[10];
    const float* bo = (const float*)d_in[11];
    float* out = (float*)d_out;

    char* ws = (char*)d_ws;
    size_t off = 0;
    auto alloc = [&](size_t bytes) {
        void* p = ws + off;
        off = (off + bytes + 255) & ~(size_t)255;
        return p;
    };
    float* xw   = (float*)alloc((size_t)NN * DH * 4);
    float* h0   = (float*)alloc((size_t)NN * DH * 4);
    float* deg  = (float*)alloc((size_t)NN * 4);
    float* dinv = (float*)alloc((size_t)NN * 4);
    int*   mode = (int*)alloc(256);
    float* h1   = (float*)alloc((size_t)NN * 500 * 4);
    float* h2   = (float*)alloc((size_t)NN * 500 * 4);

    hipMemsetAsync(deg, 0, (size_t)NN * 4, stream);
    hipMemsetAsync(h0, 0, (size_t)NN * DH * 4, stream);
    detect_mode_kernel<<<1, 1, 0, stream>>>(ei, mode);

    dim3 blk(256);
    // xw = x @ conv_W   (M=NN, N=128, K=128)
    gemm_tiled<false, false><<<dim3(2, (NN + 63) / 64), blk, 0, stream>>>(
        x, conv_W, nullptr, xw, NN, 128, 128);
    deg_kernel<<<(NE + 255) / 256, 256, 0, stream>>>(ei, mode, deg);
    dinv_kernel<<<(NN + 255) / 256, 256, 0, stream>>>(deg, dinv);
    scatter_kernel<<<(NE * 32) / 256, 256, 0, stream>>>(ei, mode, xw, dinv, h0);
    finalize_h0<<<(NN * DH + 255) / 256, 256, 0, stream>>>(xw, dinv, conv_b, h0);
    // h1 = relu(h0 @ W1 + b1)   (K=128, N=500)
    gemm_tiled<true, true><<<dim3(8, (NN + 63) / 64), blk, 0, stream>>>(
        h0, W1, b1, h1, NN, 500, 128);
    // h2 = relu(h1 @ W2 + b2)   (K=500, N=500)
    gemm_tiled<true, true><<<dim3(8, (NN + 63) / 64), blk, 0, stream>>>(
        h1, W2, b2, h2, NN, 500, 500);
    // h3 = relu(h2 @ W3 + b3) -> reuse h1
    gemm_tiled<true, true><<<dim3(8, (NN + 63) / 64), blk, 0, stream>>>(
        h2, W3, b3, h1, NN, 500, 500);
    // out = h3 @ Wo + bo
    final_gemv<<<(NN + 3) / 4, 256, 0, stream>>>(h1, Wo, bo, out);
}

// Round 3
// 1185.673 us; speedup vs baseline: 2.5791x; 2.5791x over previous
//
#include <hip/hip_runtime.h>
#include <hip/hip_bf16.h>

#define NN 50000
#define NE 800000
#define DH 128

// ---------- edge dtype detection (int32 vs int64) ----------
__global__ void detect_mode_kernel(const void* ei, int* mode) {
    if (threadIdx.x == 0 && blockIdx.x == 0) {
        const long long* p = (const long long*)ei;
        int ok64 = 1;
        for (int i = 0; i < 128; ++i) {
            long long v = p[i];
            if (v < 0 || v >= NN) { ok64 = 0; break; }
        }
        *mode = ok64;
    }
}

__device__ __forceinline__ int edge_at(const void* ei, int mode, int idx) {
    if (mode) return (int)((const long long*)ei)[idx];
    return ((const int*)ei)[idx];
}

// ---------- degree histogram (int) ----------
__global__ void deg_kernel(const void* ei, const int* mode_p, int* degi) {
    int e = blockIdx.x * blockDim.x + threadIdx.x;
    if (e >= NE) return;
    int mode = *mode_p;
    int d = edge_at(ei, mode, NE + e);
    atomicAdd(&degi[d], 1);
}

// ---------- single-block scan: off = exclusive_scan(degi); dinv = rsqrt(deg+1) ----------
__global__ __launch_bounds__(1024)
void scan_kernel(const int* __restrict__ degi, int* __restrict__ off,
                 float* __restrict__ dinv) {
    __shared__ int tmp[1024];
    __shared__ int carry;
    int tid = threadIdx.x;
    if (tid == 0) carry = 0;
    __syncthreads();
    for (int base = 0; base < NN; base += 1024) {
        int i = base + tid;
        int v = (i < NN) ? degi[i] : 0;
        if (i < NN) dinv[i] = rsqrtf((float)v + 1.0f);  // +1 self loop, always > 0
        tmp[tid] = v;
        __syncthreads();
#pragma unroll
        for (int s = 1; s < 1024; s <<= 1) {
            int t = (tid >= s) ? tmp[tid - s] : 0;
            __syncthreads();
            tmp[tid] += t;
            __syncthreads();
        }
        if (i < NN) off[i] = carry + tmp[tid] - v;  // exclusive
        __syncthreads();
        if (tid == 0) carry += tmp[1023];
        __syncthreads();
    }
}

// ---------- CSR fill: csr[off[dst] + pos] = src ----------
__global__ void fill_kernel(const void* ei, const int* mode_p,
                            const int* __restrict__ off, int* __restrict__ cursor,
                            int* __restrict__ csr) {
    int e = blockIdx.x * blockDim.x + threadIdx.x;
    if (e >= NE) return;
    int mode = *mode_p;
    int s = edge_at(ei, mode, e);
    int d = edge_at(ei, mode, NE + e);
    int pos = atomicAdd(&cursor[d], 1);
    csr[off[d] + pos] = s;
}

// ---------- gather: one wave per node, 2 feats/lane; fused self-loop+bias+relu ----------
__global__ __launch_bounds__(256)
void gather_kernel(const int* __restrict__ csr, const int* __restrict__ off,
                   const int* __restrict__ degi, const float* __restrict__ xw,
                   const float* __restrict__ dinv, const float* __restrict__ bias,
                   float* __restrict__ h0) {
    int wave = threadIdx.x >> 6;
    int lane = threadIdx.x & 63;
    int n = blockIdx.x * 4 + wave;
    if (n >= NN) return;
    int o = off[n], dg = degi[n];
    float ax = 0.f, ay = 0.f, bx = 0.f, by = 0.f;
    int j = 0;
    for (; j + 1 < dg; j += 2) {
        int s0 = csr[o + j];
        int s1 = csr[o + j + 1];
        float d0 = dinv[s0], d1 = dinv[s1];
        float2 v0 = *(const float2*)(xw + (size_t)s0 * DH + lane * 2);
        float2 v1 = *(const float2*)(xw + (size_t)s1 * DH + lane * 2);
        ax += v0.x * d0; ay += v0.y * d0;
        bx += v1.x * d1; by += v1.y * d1;
    }
    if (j < dg) {
        int s0 = csr[o + j];
        float d0 = dinv[s0];
        float2 v0 = *(const float2*)(xw + (size_t)s0 * DH + lane * 2);
        ax += v0.x * d0; ay += v0.y * d0;
    }
    float dn = dinv[n];
    float2 vs = *(const float2*)(xw + (size_t)n * DH + lane * 2);
    float rx = (ax + bx + vs.x * dn) * dn + bias[lane * 2];
    float ry = (ay + by + vs.y * dn) * dn + bias[lane * 2 + 1];
    float2 r;
    r.x = fmaxf(rx, 0.f);
    r.y = fmaxf(ry, 0.f);
    *(float2*)(h0 + (size_t)n * DH + lane * 2) = r;
}

// ---------- fp32 GEMM: 128x128 tile, 256 threads, 8x8 micro in 2x2 quadrants ----------
template <bool RELU, bool BIAS>
__global__ __launch_bounds__(256, 2)
void gemm128(const float* __restrict__ A, const float* __restrict__ B,
             const float* __restrict__ bias, float* __restrict__ C,
             int M, int N, int K) {
    __shared__ float As[16][132];
    __shared__ float Bs[16][132];
    int tid = threadIdx.x;
    int tx = tid & 15, ty = tid >> 4;
    int row0 = blockIdx.y * 128, col0 = blockIdx.x * 128;
    float acc[8][8] = {};
    for (int k0 = 0; k0 < K; k0 += 16) {
        // A: 128 rows x 16 k = 2048 elems; each thread stages TWO float4s
        // (rows tid>>2 and 64+(tid>>2)). Round-2 bug: only rows 0..63 staged.
        {
            int kq = tid & 3;
            int k = k0 + kq * 4;
#pragma unroll
            for (int p = 0; p < 2; ++p) {
                int r = (tid >> 2) + p * 64;
                int row = row0 + r;
                float4 v = {0.f, 0.f, 0.f, 0.f};
                if (row < M) {
                    if (k + 3 < K) {
                        v = *(const float4*)(A + (size_t)row * K + k);
                    } else {
                        float t0 = (k + 0 < K) ? A[(size_t)row * K + k + 0] : 0.f;
                        float t1 = (k + 1 < K) ? A[(size_t)row * K + k + 1] : 0.f;
                        float t2 = (k + 2 < K) ? A[(size_t)row * K + k + 2] : 0.f;
                        float t3 = (k + 3 < K) ? A[(size_t)row * K + k + 3] : 0.f;
                        v = {t0, t1, t2, t3};
                    }
                }
                As[kq * 4 + 0][r] = v.x;
                As[kq * 4 + 1][r] = v.y;
                As[kq * 4 + 2][r] = v.z;
                As[kq * 4 + 3][r] = v.w;
            }
        }
        // B: 16 k x 128 cols. thread: col = (tid&31)*4, kk = tid>>5 (+8)
        {
            int c = (tid & 31) * 4;
            int col = col0 + c;
#pragma unroll
            for (int p = 0; p < 2; ++p) {
                int kk = (tid >> 5) + p * 8;
                int k = k0 + kk;
                float4 v = {0.f, 0.f, 0.f, 0.f};
                if (k < K) {
                    if (col + 3 < N) {
                        v = *(const float4*)(B + (size_t)k * N + col);
                    } else {
                        float t0 = (col + 0 < N) ? B[(size_t)k * N + col + 0] : 0.f;
                        float t1 = (col + 1 < N) ? B[(size_t)k * N + col + 1] : 0.f;
                        float t2 = (col + 2 < N) ? B[(size_t)k * N + col + 2] : 0.f;
                        float t3 = (col + 3 < N) ? B[(size_t)k * N + col + 3] : 0.f;
                        v = {t0, t1, t2, t3};
                    }
                }
                *(float4*)&Bs[kk][c] = v;
            }
        }
        __syncthreads();
#pragma unroll
        for (int kk = 0; kk < 16; ++kk) {
            float a[8], b[8];
            *(float4*)&a[0] = *(const float4*)&As[kk][ty * 4];
            *(float4*)&a[4] = *(const float4*)&As[kk][64 + ty * 4];
            *(float4*)&b[0] = *(const float4*)&Bs[kk][tx * 4];
            *(float4*)&b[4] = *(const float4*)&Bs[kk][64 + tx * 4];
#pragma unroll
            for (int i = 0; i < 8; ++i)
#pragma unroll
                for (int jj = 0; jj < 8; ++jj) acc[i][jj] += a[i] * b[jj];
        }
        __syncthreads();
    }
    // write 2x2 quadrants of 4x4 float4 rows
#pragma unroll
    for (int i = 0; i < 8; ++i) {
        int row = row0 + (i < 4 ? ty * 4 + i : 64 + ty * 4 + (i - 4));
        if (row >= M) continue;
#pragma unroll
        for (int jh = 0; jh < 2; ++jh) {
            int col = col0 + (jh == 0 ? tx * 4 : 64 + tx * 4);
            if (col + 3 < N) {
                float4 v = {acc[i][jh * 4 + 0], acc[i][jh * 4 + 1],
                            acc[i][jh * 4 + 2], acc[i][jh * 4 + 3]};
                if (BIAS) {
                    const float4 bv = *(const float4*)(bias + col);
                    v.x += bv.x; v.y += bv.y; v.z += bv.z; v.w += bv.w;
                }
                if (RELU) {
                    v.x = fmaxf(v.x, 0.f); v.y = fmaxf(v.y, 0.f);
                    v.z = fmaxf(v.z, 0.f); v.w = fmaxf(v.w, 0.f);
                }
                *(float4*)(C + (size_t)row * N + col) = v;
            } else {
#pragma unroll
                for (int u = 0; u < 4; ++u) {
                    if (col + u < N) {
                        float v = acc[i][jh * 4 + u];
                        if (BIAS) v += bias[col + u];
                        if (RELU) v = fmaxf(v, 0.f);
                        C[(size_t)row * N + col + u] = v;
                    }
                }
            }
        }
    }
}

// ---------- final layer: out[i] = dot(H[i,:500], Wo) + bo ----------
__global__ void final_gemv(const float* __restrict__ H, const float* __restrict__ Wo,
                           const float* __restrict__ bo, float* __restrict__ out) {
    int wave = threadIdx.x >> 6;
    int lane = threadIdx.x & 63;
    int row = blockIdx.x * 4 + wave;
    if (row >= NN) return;
    const float* h = H + (size_t)row * 500;
    float s = 0.f;
    for (int k = lane; k < 500; k += 64) s += h[k] * Wo[k];
#pragma unroll
    for (int off = 32; off > 0; off >>= 1) s += __shfl_down(s, off, 64);
    if (lane == 0) out[row] = s + bo[0];
}

extern "C" void kernel_launch(void* const* d_in, const int* in_sizes, int n_in,
                              void* d_out, int out_size, void* d_ws, size_t ws_size,
                              hipStream_t stream) {
    const float* x      = (const float*)d_in[0];
    const void*  ei     = d_in[1];
    const float* conv_W = (const float*)d_in[2];
    const float* conv_b = (const float*)d_in[3];
    const float* W1 = (const float*)d_in[4];
    const float* b1 = (const float*)d_in[5];
    const float* W2 = (const float*)d_in[6];
    const float* b2 = (const float*)d_in[7];
    const float* W3 = (const float*)d_in[8];
    const float* b3 = (const float*)d_in[9];
    const float* Wo = (const float*)d_in[10];
    const float* bo = (const float*)d_in[11];
    float* out = (float*)d_out;

    char* ws = (char*)d_ws;
    size_t off_b = 0;
    auto alloc = [&](size_t bytes) {
        void* p = ws + off_b;
        off_b = (off_b + bytes + 255) & ~(size_t)255;
        return p;
    };
    float* xw = (float*)alloc((size_t)NN * DH * 4);   // 25.6 MB
    float* h0 = (float*)alloc((size_t)NN * DH * 4);   // 25.6 MB
    float* h1 = (float*)alloc((size_t)NN * 500 * 4);  // 100 MB
    float* h2 = (float*)alloc((size_t)NN * 500 * 4);  // 100 MB
    // CSR metadata aliases into h2's space: written steps 1-4, dead after gather,
    // h2 is first written only by the L2 GEMM afterwards.
    char* meta = (char*)h2;
    int*   degi   = (int*)(meta);                 // 200 KB
    int*   offn   = (int*)(meta + 1 * 262144);    // 200 KB
    int*   cursor = (int*)(meta + 2 * 262144);    // 200 KB
    float* dinv   = (float*)(meta + 3 * 262144);  // 200 KB
    int*   mode   = (int*)(meta + 4 * 262144);
    int*   csr    = (int*)(meta + 5 * 262144);    // 3.2 MB

    hipMemsetAsync(degi, 0, (size_t)NN * 4, stream);
    hipMemsetAsync(cursor, 0, (size_t)NN * 4, stream);
    detect_mode_kernel<<<1, 1, 0, stream>>>(ei, mode);

    // xw = x @ conv_W   (M=NN, N=128, K=128)
    gemm128<false, false><<<dim3(1, (NN + 127) / 128), 256, 0, stream>>>(
        x, conv_W, nullptr, xw, NN, 128, 128);

    deg_kernel<<<(NE + 255) / 256, 256, 0, stream>>>(ei, mode, degi);
    scan_kernel<<<1, 1024, 0, stream>>>(degi, offn, dinv);
    fill_kernel<<<(NE + 255) / 256, 256, 0, stream>>>(ei, mode, offn, cursor, csr);
    gather_kernel<<<(NN + 3) / 4, 256, 0, stream>>>(csr, offn, degi, xw, dinv, conv_b, h0);

    // h1 = relu(h0 @ W1 + b1)   (K=128, N=500)
    gemm128<true, true><<<dim3(4, (NN + 127) / 128), 256, 0, stream>>>(
        h0, W1, b1, h1, NN, 500, 128);
    // h2 = relu(h1 @ W2 + b2)   (K=500, N=500)
    gemm128<true, true><<<dim3(4, (NN + 127) / 128), 256, 0, stream>>>(
        h1, W2, b2, h2, NN, 500, 500);
    // h3 = relu(h2 @ W3 + b3) -> back into h1
    gemm128<true, true><<<dim3(4, (NN + 127) / 128), 256, 0, stream>>>(
        h2, W3, b3, h1, NN, 500, 500);
    // out = h3 @ Wo + bo
    final_gemv<<<(NN + 3) / 4, 256, 0, stream>>>(h1, Wo, bo, out);
}

// Round 4
// 395.803 us; speedup vs baseline: 7.7260x; 2.9956x over previous
//
#include <hip/hip_runtime.h>
#include <hip/hip_bf16.h>
#include <hip/hip_fp16.h>

#define NN 50000
#define NE 800000

typedef _Float16 f16;
typedef _Float16 f16x2 __attribute__((ext_vector_type(2)));
typedef _Float16 f16x8 __attribute__((ext_vector_type(8)));
typedef float f32x4 __attribute__((ext_vector_type(4)));

// ---------- async global->LDS 16B ----------
__device__ __forceinline__ void gload16(const f16* g, f16* l) {
    __builtin_amdgcn_global_load_lds(
        (__attribute__((address_space(1))) void*)(void*)g,
        (__attribute__((address_space(3))) void*)(void*)l, 16, 0, 0);
}

// ---------- edge dtype detection (int32 vs int64) ----------
__global__ void detect_mode_kernel(const void* ei, int* mode) {
    if (threadIdx.x == 0 && blockIdx.x == 0) {
        const long long* p = (const long long*)ei;
        int ok64 = 1;
        for (int i = 0; i < 128; ++i) {
            long long v = p[i];
            if (v < 0 || v >= NN) { ok64 = 0; break; }
        }
        *mode = ok64;
    }
}

__device__ __forceinline__ int edge_at(const void* ei, int mode, int idx) {
    if (mode) return (int)((const long long*)ei)[idx];
    return ((const int*)ei)[idx];
}

// ---------- degree histogram ----------
__global__ void deg_kernel(const void* ei, const int* mode_p, int* degi) {
    int e = blockIdx.x * blockDim.x + threadIdx.x;
    if (e >= NE) return;
    int mode = *mode_p;
    int d = edge_at(ei, mode, NE + e);
    atomicAdd(&degi[d], 1);
}

// ---------- 3-phase scan ----------
#define NBLK 49
__global__ __launch_bounds__(1024)
void scan_blocksum(const int* __restrict__ degi, int* __restrict__ bsum) {
    __shared__ int red[1024];
    int i = blockIdx.x * 1024 + threadIdx.x;
    red[threadIdx.x] = (i < NN) ? degi[i] : 0;
    __syncthreads();
    for (int s = 512; s > 0; s >>= 1) {
        if (threadIdx.x < s) red[threadIdx.x] += red[threadIdx.x + s];
        __syncthreads();
    }
    if (threadIdx.x == 0) bsum[blockIdx.x] = red[0];
}
__global__ void scan_top(const int* __restrict__ bsum, int* __restrict__ boff) {
    if (threadIdx.x == 0) {
        int acc = 0;
        for (int b = 0; b < NBLK; ++b) { boff[b] = acc; acc += bsum[b]; }
    }
}
__global__ __launch_bounds__(1024)
void scan_apply(const int* __restrict__ degi, const int* __restrict__ boff,
                int* __restrict__ off, float* __restrict__ dinv) {
    __shared__ int tmp[1024];
    int tid = threadIdx.x;
    int i = blockIdx.x * 1024 + tid;
    int v = (i < NN) ? degi[i] : 0;
    tmp[tid] = v;
    __syncthreads();
    for (int s = 1; s < 1024; s <<= 1) {
        int t = (tid >= s) ? tmp[tid - s] : 0;
        __syncthreads();
        tmp[tid] += t;
        __syncthreads();
    }
    if (i < NN) {
        off[i] = boff[blockIdx.x] + tmp[tid] - v;   // exclusive
        dinv[i] = rsqrtf((float)v + 1.0f);          // +1 self loop
    }
}

// ---------- CSR fill ----------
__global__ void fill_kernel(const void* ei, const int* mode_p,
                            const int* __restrict__ off, int* __restrict__ cursor,
                            int* __restrict__ csr) {
    int e = blockIdx.x * blockDim.x + threadIdx.x;
    if (e >= NE) return;
    int mode = *mode_p;
    int s = edge_at(ei, mode, e);
    int d = edge_at(ei, mode, NE + e);
    int pos = atomicAdd(&cursor[d], 1);
    csr[off[d] + pos] = s;
}

// ---------- gather (fp16 xw -> fp16 h0, fused self-loop+bias+relu) ----------
__global__ __launch_bounds__(256)
void gather_kernel(const int* __restrict__ csr, const int* __restrict__ off,
                   const int* __restrict__ degi, const f16* __restrict__ xwh,
                   const float* __restrict__ dinv, const float* __restrict__ conv_b,
                   f16* __restrict__ h0h) {
    int wv = threadIdx.x >> 6, lane = threadIdx.x & 63;
    int n = blockIdx.x * 4 + wv;
    if (n >= NN) return;
    int o = off[n], dg = degi[n];
    float ax = 0.f, ay = 0.f, bx = 0.f, by = 0.f;
    int j = 0;
    for (; j + 1 < dg; j += 2) {
        int s0 = csr[o + j], s1 = csr[o + j + 1];
        float d0 = dinv[s0], d1 = dinv[s1];
        f16x2 v0 = *(const f16x2*)(xwh + (size_t)s0 * 128 + lane * 2);
        f16x2 v1 = *(const f16x2*)(xwh + (size_t)s1 * 128 + lane * 2);
        ax += (float)v0[0] * d0; ay += (float)v0[1] * d0;
        bx += (float)v1[0] * d1; by += (float)v1[1] * d1;
    }
    if (j < dg) {
        int s0 = csr[o + j];
        float d0 = dinv[s0];
        f16x2 v0 = *(const f16x2*)(xwh + (size_t)s0 * 128 + lane * 2);
        ax += (float)v0[0] * d0; ay += (float)v0[1] * d0;
    }
    float dn = dinv[n];
    f16x2 vs = *(const f16x2*)(xwh + (size_t)n * 128 + lane * 2);
    float rx = (ax + bx + (float)vs[0] * dn) * dn + conv_b[lane * 2];
    float ry = (ay + by + (float)vs[1] * dn) * dn + conv_b[lane * 2 + 1];
    f16x2 r;
    r[0] = (f16)fmaxf(rx, 0.f);
    r[1] = (f16)fmaxf(ry, 0.f);
    *(f16x2*)(h0h + (size_t)n * 128 + lane * 2) = r;
}

// ---------- input conversions ----------
__global__ void convert_x(const float* __restrict__ x, f16* __restrict__ xh) {
    int i = (blockIdx.x * 256 + threadIdx.x) * 8;
    if (i >= NN * 128) return;
    float4 u0 = *(const float4*)(x + i);
    float4 u1 = *(const float4*)(x + i + 4);
    f16x8 o;
    o[0] = (f16)u0.x; o[1] = (f16)u0.y; o[2] = (f16)u0.z; o[3] = (f16)u0.w;
    o[4] = (f16)u1.x; o[5] = (f16)u1.y; o[6] = (f16)u1.z; o[7] = (f16)u1.w;
    *(f16x8*)(xh + i) = o;
}

// weights: W[K][N] fp32 -> WT[Npad][Kpad] fp16 (zero-padded); biases padded fp32
__global__ void prep_weights(const float* __restrict__ cW, const float* __restrict__ W1,
                             const float* __restrict__ W2, const float* __restrict__ W3,
                             const float* __restrict__ Wo, const float* __restrict__ b1,
                             const float* __restrict__ b2, const float* __restrict__ b3,
                             f16* __restrict__ cWT, f16* __restrict__ W1T,
                             f16* __restrict__ W2T, f16* __restrict__ W3T,
                             float* __restrict__ Wof, float* __restrict__ b1p,
                             float* __restrict__ b2p, float* __restrict__ b3p) {
    int i = blockIdx.x * 256 + threadIdx.x;
    if (i < 16384) { int n = i >> 7, k = i & 127; cWT[i] = (f16)cW[k * 128 + n]; return; }
    i -= 16384;
    if (i < 65536) { int n = i >> 7, k = i & 127; W1T[i] = (f16)((n < 500) ? W1[k * 500 + n] : 0.f); return; }
    i -= 65536;
    if (i < 262144) { int n = i >> 9, k = i & 511; W2T[i] = (f16)((n < 500 && k < 500) ? W2[k * 500 + n] : 0.f); return; }
    i -= 262144;
    if (i < 262144) { int n = i >> 9, k = i & 511; W3T[i] = (f16)((n < 500 && k < 500) ? W3[k * 500 + n] : 0.f); return; }
    i -= 262144;
    if (i < 512) { Wof[i] = (i < 500) ? Wo[i] : 0.f; return; }
    i -= 512;
    if (i < 512) { b1p[i] = (i < 500) ? b1[i] : 0.f; return; }
    i -= 512;
    if (i < 512) { b2p[i] = (i < 500) ? b2[i] : 0.f; return; }
    i -= 512;
    if (i < 512) { b3p[i] = (i < 500) ? b3[i] : 0.f; return; }
}

// ---------- MFMA f16 GEMM: C[M][Npad] = [relu]( A[M][K] @ BT[Npad][K]^T [+ biasp] )
// 128x128 tile, 4 waves (2x2), BK=32, double-buffered LDS via global_load_lds(16B),
// XOR slot swizzle (pre-swizzled global source) -> 4-way read conflict max.
template <bool RELU, bool BIAS>
__global__ __launch_bounds__(256)
void mfma_gemm(const f16* __restrict__ A, const f16* __restrict__ Bt,
               const float* __restrict__ biasp, f16* __restrict__ C,
               int M, int Npad, int K) {
    __shared__ f16 As[2][4096];
    __shared__ f16 Bs[2][4096];
    const int tid = threadIdx.x;
    const int lane = tid & 63;
    const int wm = (tid >> 6) >> 1, wn = (tid >> 6) & 1;
    const int l15 = lane & 15, lk = lane >> 4;
    const int row0 = blockIdx.y * 128, col0 = blockIdx.x * 128;

    // staging: slot s (0..511 per matrix), m/n = s>>2, physical 16B col = s&3,
    // global k-group = (s&3) ^ (m&3)  [involution; read applies same XOR]
    size_t abase[2], bbase[2];
#pragma unroll
    for (int i = 0; i < 2; ++i) {
        int s = tid + i * 256;
        int m = s >> 2;
        int kgp = (s & 3) ^ (m & 3);
        int row = row0 + m; if (row > M - 1) row = M - 1;   // clamp: garbage rows, not stored
        abase[i] = (size_t)row * K + kgp * 8;
        bbase[i] = (size_t)(col0 + m) * K + kgp * 8;
    }
    const int fragoff = l15 * 32 + ((lk ^ (l15 & 3)) * 8);  // halves
    f32x4 acc[4][4] = {};

    const int nt = K >> 5;
#pragma unroll
    for (int i = 0; i < 2; ++i) {
        gload16(A + abase[i], &As[0][tid * 8 + i * 2048]);
        gload16(Bt + bbase[i], &Bs[0][tid * 8 + i * 2048]);
    }
    __syncthreads();
    int cur = 0;
    for (int t = 0; t < nt; ++t) {
        if (t + 1 < nt) {
            int k0 = (t + 1) << 5;
#pragma unroll
            for (int i = 0; i < 2; ++i) {
                gload16(A + abase[i] + k0, &As[cur ^ 1][tid * 8 + i * 2048]);
                gload16(Bt + bbase[i] + k0, &Bs[cur ^ 1][tid * 8 + i * 2048]);
            }
        }
        f16x8 af[4], bf[4];
#pragma unroll
        for (int f = 0; f < 4; ++f) {
            af[f] = *(const f16x8*)&As[cur][(wm * 64 + f * 16) * 32 + fragoff];
            bf[f] = *(const f16x8*)&Bs[cur][(wn * 64 + f * 16) * 32 + fragoff];
        }
#pragma unroll
        for (int fi = 0; fi < 4; ++fi)
#pragma unroll
            for (int fj = 0; fj < 4; ++fj)
                acc[fi][fj] = __builtin_amdgcn_mfma_f32_16x16x32_f16(
                    af[fi], bf[fj], acc[fi][fj], 0, 0, 0);
        __syncthreads();
        cur ^= 1;
    }
    // epilogue: D row = (lane>>4)*4 + reg, col = lane&15 (m89-verified layout)
#pragma unroll
    for (int fi = 0; fi < 4; ++fi)
#pragma unroll
        for (int r = 0; r < 4; ++r) {
            int row = row0 + wm * 64 + fi * 16 + lk * 4 + r;
            if (row < M) {
#pragma unroll
                for (int fj = 0; fj < 4; ++fj) {
                    int n = col0 + wn * 64 + fj * 16 + l15;
                    float v = acc[fi][fj][r];
                    if (BIAS) v += biasp[n];
                    if (RELU) v = fmaxf(v, 0.f);
                    C[(size_t)row * Npad + n] = (f16)v;
                }
            }
        }
}

// ---------- final layer ----------
__global__ __launch_bounds__(256)
void final_gemv(const f16* __restrict__ H, const float* __restrict__ Wof,
                const float* __restrict__ bo, float* __restrict__ out) {
    int wv = threadIdx.x >> 6, lane = threadIdx.x & 63;
    int row = blockIdx.x * 4 + wv;
    if (row >= NN) return;
    f16x8 hv = *(const f16x8*)(H + (size_t)row * 512 + lane * 8);
    float s = 0.f;
#pragma unroll
    for (int j = 0; j < 8; ++j) s += (float)hv[j] * Wof[lane * 8 + j];
#pragma unroll
    for (int o = 32; o > 0; o >>= 1) s += __shfl_down(s, o, 64);
    if (lane == 0) out[row] = s + bo[0];
}

extern "C" void kernel_launch(void* const* d_in, const int* in_sizes, int n_in,
                              void* d_out, int out_size, void* d_ws, size_t ws_size,
                              hipStream_t stream) {
    const float* x      = (const float*)d_in[0];
    const void*  ei     = d_in[1];
    const float* conv_W = (const float*)d_in[2];
    const float* conv_b = (const float*)d_in[3];
    const float* W1 = (const float*)d_in[4];
    const float* b1 = (const float*)d_in[5];
    const float* W2 = (const float*)d_in[6];
    const float* b2 = (const float*)d_in[7];
    const float* W3 = (const float*)d_in[8];
    const float* b3 = (const float*)d_in[9];
    const float* Wo = (const float*)d_in[10];
    const float* bo = (const float*)d_in[11];
    float* out = (float*)d_out;

    char* ws = (char*)d_ws;
    size_t off_b = 0;
    auto alloc = [&](size_t bytes) {
        void* p = ws + off_b;
        off_b = (off_b + bytes + 255) & ~(size_t)255;
        return p;
    };
    f16*   xh   = (f16*)alloc((size_t)NN * 128 * 2);
    f16*   xwh  = (f16*)alloc((size_t)NN * 128 * 2);
    f16*   h0h  = (f16*)alloc((size_t)NN * 128 * 2);
    f16*   h1h  = (f16*)alloc((size_t)NN * 512 * 2);
    f16*   h2h  = (f16*)alloc((size_t)NN * 512 * 2);
    f16*   cWT  = (f16*)alloc(128 * 128 * 2);
    f16*   W1T  = (f16*)alloc(512 * 128 * 2);
    f16*   W2T  = (f16*)alloc(512 * 512 * 2);
    f16*   W3T  = (f16*)alloc(512 * 512 * 2);
    float* Wof  = (float*)alloc(512 * 4);
    float* b1p  = (float*)alloc(512 * 4);
    float* b2p  = (float*)alloc(512 * 4);
    float* b3p  = (float*)alloc(512 * 4);
    int*   degi   = (int*)alloc(NN * 4);
    int*   offn   = (int*)alloc(NN * 4);
    int*   cursor = (int*)alloc(NN * 4);
    float* dinv   = (float*)alloc(NN * 4);
    int*   bsum   = (int*)alloc(NBLK * 4);
    int*   boff   = (int*)alloc(NBLK * 4);
    int*   mode   = (int*)alloc(256);
    int*   csr    = (int*)alloc((size_t)NE * 4);

    hipMemsetAsync(degi, 0, (size_t)NN * 4, stream);
    hipMemsetAsync(cursor, 0, (size_t)NN * 4, stream);
    detect_mode_kernel<<<1, 1, 0, stream>>>(ei, mode);
    convert_x<<<(NN * 128 / 8 + 255) / 256, 256, 0, stream>>>(x, xh);
    prep_weights<<<(608256 + 255) / 256, 256, 0, stream>>>(
        conv_W, W1, W2, W3, Wo, b1, b2, b3, cWT, W1T, W2T, W3T, Wof, b1p, b2p, b3p);

    // xw = x @ conv_W   (fp16 out)
    mfma_gemm<false, false><<<dim3(1, 391), 256, 0, stream>>>(
        xh, cWT, nullptr, xwh, NN, 128, 128);

    deg_kernel<<<(NE + 255) / 256, 256, 0, stream>>>(ei, mode, degi);
    scan_blocksum<<<NBLK, 1024, 0, stream>>>(degi, bsum);
    scan_top<<<1, 64, 0, stream>>>(bsum, boff);
    scan_apply<<<NBLK, 1024, 0, stream>>>(degi, boff, offn, dinv);
    fill_kernel<<<(NE + 255) / 256, 256, 0, stream>>>(ei, mode, offn, cursor, csr);
    gather_kernel<<<(NN + 3) / 4, 256, 0, stream>>>(csr, offn, degi, xwh, dinv, conv_b, h0h);

    // h1 = relu(h0 @ W1 + b1)
    mfma_gemm<true, true><<<dim3(4, 391), 256, 0, stream>>>(
        h0h, W1T, b1p, h1h, NN, 512, 128);
    // h2 = relu(h1 @ W2 + b2)
    mfma_gemm<true, true><<<dim3(4, 391), 256, 0, stream>>>(
        h1h, W2T, b2p, h2h, NN, 512, 512);
    // h3 = relu(h2 @ W3 + b3) -> reuse h1h
    mfma_gemm<true, true><<<dim3(4, 391), 256, 0, stream>>>(
        h2h, W3T, b3p, h1h, NN, 512, 512);
    // out = h3 @ Wo + bo
    final_gemv<<<(NN + 3) / 4, 256, 0, stream>>>(h1h, Wof, bo, out);
}

// Round 5
// 375.148 us; speedup vs baseline: 8.1513x; 1.0551x over previous
//
#include <hip/hip_runtime.h>
#include <hip/hip_bf16.h>
#include <hip/hip_fp16.h>

#define NN 50000
#define NE 800000

typedef _Float16 f16;
typedef _Float16 f16x2 __attribute__((ext_vector_type(2)));
typedef _Float16 f16x8 __attribute__((ext_vector_type(8)));
typedef float f32x4 __attribute__((ext_vector_type(4)));

// ---------- async global->LDS 16B ----------
__device__ __forceinline__ void gload16(const f16* g, f16* l) {
    __builtin_amdgcn_global_load_lds(
        (__attribute__((address_space(1))) void*)(void*)g,
        (__attribute__((address_space(3))) void*)(void*)l, 16, 0, 0);
}

// ---------- inline edge dtype detection (int32 vs int64) ----------
// int32 data misread as int64 pairs (lo,hi): hi is itself a node index, P(hi==0
// for all 8 samples) < 1e-37 -> detection is exact in practice.
__device__ __forceinline__ int detect_mode(const void* ei) {
    const long long* p = (const long long*)ei;
    int ok = 1;
#pragma unroll
    for (int i = 0; i < 8; ++i) {
        long long v = p[i];
        if (v < 0 || v >= NN) ok = 0;
    }
    return ok;
}

__device__ __forceinline__ int edge_at(const void* ei, int mode, int idx) {
    if (mode) return (int)((const long long*)ei)[idx];
    return ((const int*)ei)[idx];
}

// ---------- degree histogram ----------
__global__ void deg_kernel(const void* ei, int* degi) {
    int e = blockIdx.x * blockDim.x + threadIdx.x;
    if (e >= NE) return;
    int mode = detect_mode(ei);
    int d = edge_at(ei, mode, NE + e);
    atomicAdd(&degi[d], 1);
}

// ---------- 3-phase scan ----------
#define NBLK 49
__global__ __launch_bounds__(1024)
void scan_blocksum(const int* __restrict__ degi, int* __restrict__ bsum) {
    __shared__ int red[1024];
    int i = blockIdx.x * 1024 + threadIdx.x;
    red[threadIdx.x] = (i < NN) ? degi[i] : 0;
    __syncthreads();
    for (int s = 512; s > 0; s >>= 1) {
        if (threadIdx.x < s) red[threadIdx.x] += red[threadIdx.x + s];
        __syncthreads();
    }
    if (threadIdx.x == 0) bsum[blockIdx.x] = red[0];
}
__global__ void scan_top(const int* __restrict__ bsum, int* __restrict__ boff) {
    if (threadIdx.x == 0) {
        int acc = 0;
        for (int b = 0; b < NBLK; ++b) { boff[b] = acc; acc += bsum[b]; }
    }
}
// also: dinv = rsqrt(deg+1); out[i] = bo[0] (pre-init for fused final layer)
__global__ __launch_bounds__(1024)
void scan_apply(const int* __restrict__ degi, const int* __restrict__ boff,
                int* __restrict__ off, float* __restrict__ dinv,
                const float* __restrict__ bo, float* __restrict__ out) {
    __shared__ int tmp[1024];
    int tid = threadIdx.x;
    int i = blockIdx.x * 1024 + tid;
    int v = (i < NN) ? degi[i] : 0;
    tmp[tid] = v;
    __syncthreads();
    for (int s = 1; s < 1024; s <<= 1) {
        int t = (tid >= s) ? tmp[tid - s] : 0;
        __syncthreads();
        tmp[tid] += t;
        __syncthreads();
    }
    if (i < NN) {
        off[i] = boff[blockIdx.x] + tmp[tid] - v;   // exclusive
        dinv[i] = rsqrtf((float)v + 1.0f);          // +1 self loop
        out[i] = bo[0];
    }
}

// ---------- CSR fill ----------
__global__ void fill_kernel(const void* ei,
                            const int* __restrict__ off, int* __restrict__ cursor,
                            int* __restrict__ csr) {
    int e = blockIdx.x * blockDim.x + threadIdx.x;
    if (e >= NE) return;
    int mode = detect_mode(ei);
    int s = edge_at(ei, mode, e);
    int d = edge_at(ei, mode, NE + e);
    int pos = atomicAdd(&cursor[d], 1);
    csr[off[d] + pos] = s;
}

// ---------- gather (fp16 xw -> fp16 h0, fused self-loop+bias+relu) ----------
__global__ __launch_bounds__(256)
void gather_kernel(const int* __restrict__ csr, const int* __restrict__ off,
                   const int* __restrict__ degi, const f16* __restrict__ xwh,
                   const float* __restrict__ dinv, const float* __restrict__ conv_b,
                   f16* __restrict__ h0h) {
    int wv = threadIdx.x >> 6, lane = threadIdx.x & 63;
    int n = blockIdx.x * 4 + wv;
    if (n >= NN) return;
    int o = off[n], dg = degi[n];
    float ax = 0.f, ay = 0.f, bx = 0.f, by = 0.f;
    int j = 0;
    for (; j + 1 < dg; j += 2) {
        int s0 = csr[o + j], s1 = csr[o + j + 1];
        float d0 = dinv[s0], d1 = dinv[s1];
        f16x2 v0 = *(const f16x2*)(xwh + (size_t)s0 * 128 + lane * 2);
        f16x2 v1 = *(const f16x2*)(xwh + (size_t)s1 * 128 + lane * 2);
        ax += (float)v0[0] * d0; ay += (float)v0[1] * d0;
        bx += (float)v1[0] * d1; by += (float)v1[1] * d1;
    }
    if (j < dg) {
        int s0 = csr[o + j];
        float d0 = dinv[s0];
        f16x2 v0 = *(const f16x2*)(xwh + (size_t)s0 * 128 + lane * 2);
        ax += (float)v0[0] * d0; ay += (float)v0[1] * d0;
    }
    float dn = dinv[n];
    f16x2 vs = *(const f16x2*)(xwh + (size_t)n * 128 + lane * 2);
    float rx = (ax + bx + (float)vs[0] * dn) * dn + conv_b[lane * 2];
    float ry = (ay + by + (float)vs[1] * dn) * dn + conv_b[lane * 2 + 1];
    f16x2 r;
    r[0] = (f16)fmaxf(rx, 0.f);
    r[1] = (f16)fmaxf(ry, 0.f);
    *(f16x2*)(h0h + (size_t)n * 128 + lane * 2) = r;
}

// ---------- merged prep: x->fp16 AND weights transpose/pad/convert ----------
__global__ void prep_all(const float* __restrict__ x, f16* __restrict__ xh,
                         const float* __restrict__ cW, const float* __restrict__ W1,
                         const float* __restrict__ W2, const float* __restrict__ W3,
                         const float* __restrict__ Wo, const float* __restrict__ b1,
                         const float* __restrict__ b2, const float* __restrict__ b3,
                         f16* __restrict__ cWT, f16* __restrict__ W1T,
                         f16* __restrict__ W2T, f16* __restrict__ W3T,
                         float* __restrict__ Wof, float* __restrict__ b1p,
                         float* __restrict__ b2p, float* __restrict__ b3p) {
    int i = blockIdx.x * 256 + threadIdx.x;
    if (i < 800000) {               // convert x, 8 elems/thread
        int e = i * 8;
        float4 u0 = *(const float4*)(x + e);
        float4 u1 = *(const float4*)(x + e + 4);
        f16x8 o;
        o[0] = (f16)u0.x; o[1] = (f16)u0.y; o[2] = (f16)u0.z; o[3] = (f16)u0.w;
        o[4] = (f16)u1.x; o[5] = (f16)u1.y; o[6] = (f16)u1.z; o[7] = (f16)u1.w;
        *(f16x8*)(xh + e) = o;
        return;
    }
    i -= 800000;
    if (i < 16384) { int n = i >> 7, k = i & 127; cWT[i] = (f16)cW[k * 128 + n]; return; }
    i -= 16384;
    if (i < 65536) { int n = i >> 7, k = i & 127; W1T[i] = (f16)((n < 500) ? W1[k * 500 + n] : 0.f); return; }
    i -= 65536;
    if (i < 262144) { int n = i >> 9, k = i & 511; W2T[i] = (f16)((n < 500 && k < 500) ? W2[k * 500 + n] : 0.f); return; }
    i -= 262144;
    if (i < 262144) { int n = i >> 9, k = i & 511; W3T[i] = (f16)((n < 500 && k < 500) ? W3[k * 500 + n] : 0.f); return; }
    i -= 262144;
    if (i < 512) { Wof[i] = (i < 500) ? Wo[i] : 0.f; return; }
    i -= 512;
    if (i < 512) { b1p[i] = (i < 500) ? b1[i] : 0.f; return; }
    i -= 512;
    if (i < 512) { b2p[i] = (i < 500) ? b2[i] : 0.f; return; }
    i -= 512;
    if (i < 512) { b3p[i] = (i < 500) ? b3[i] : 0.f; return; }
}

// ---------- MFMA f16 GEMM ----------
// 128x128 tile, 4 waves (2x2), BK=32, dbuf LDS via global_load_lds(16B),
// XOR slot swizzle (pre-swizzled global source).
// SWZ: panel-group block swizzle -- all 4 col-blocks of a 128-row panel land on
//      the same XCD (ids congruent mod 8, 8 apart) so the A panel is fetched
//      once into that XCD's L2. Requires gridDim=(4, 392).
// FUSE: don't store C; dot fp32 row tiles with Wof and atomicAdd into out
//      (final layer fused; out pre-initialized to bo).
template <bool SWZ, bool RELU, bool BIAS, bool FUSE>
__global__ __launch_bounds__(256)
void mfma_gemm(const f16* __restrict__ A, const f16* __restrict__ Bt,
               const float* __restrict__ biasp, f16* __restrict__ C,
               const float* __restrict__ Wof, float* __restrict__ out,
               int M, int Npad, int K) {
    int bx, by;
    if (SWZ) {
        int id = blockIdx.x + 4 * blockIdx.y;
        int x = id & 7, s = id >> 3;
        bx = s & 3;
        by = (s >> 2) * 8 + x;
        if (by * 128 >= M) return;   // uniform: padded panel
    } else {
        bx = blockIdx.x; by = blockIdx.y;
    }
    __shared__ f16 As[2][4096];
    __shared__ f16 Bs[2][4096];
    const int tid = threadIdx.x;
    const int lane = tid & 63;
    const int wm = (tid >> 6) >> 1, wn = (tid >> 6) & 1;
    const int l15 = lane & 15, lk = lane >> 4;
    const int row0 = by * 128, col0 = bx * 128;

    // staging: slot s (0..511 per matrix), m/n = s>>2, physical 16B col = s&3,
    // global k-group = (s&3) ^ (m&3)  [involution; read applies same XOR]
    size_t abase[2], bbase[2];
#pragma unroll
    for (int i = 0; i < 2; ++i) {
        int s = tid + i * 256;
        int m = s >> 2;
        int kgp = (s & 3) ^ (m & 3);
        int row = row0 + m; if (row > M - 1) row = M - 1;   // clamp: garbage rows, not stored
        abase[i] = (size_t)row * K + kgp * 8;
        bbase[i] = (size_t)(col0 + m) * K + kgp * 8;
    }
    const int fragoff = l15 * 32 + ((lk ^ (l15 & 3)) * 8);  // halves
    f32x4 acc[4][4] = {};

    const int nt = K >> 5;
#pragma unroll
    for (int i = 0; i < 2; ++i) {
        gload16(A + abase[i], &As[0][tid * 8 + i * 2048]);
        gload16(Bt + bbase[i], &Bs[0][tid * 8 + i * 2048]);
    }
    __syncthreads();
    int cur = 0;
    for (int t = 0; t < nt; ++t) {
        if (t + 1 < nt) {
            int k0 = (t + 1) << 5;
#pragma unroll
            for (int i = 0; i < 2; ++i) {
                gload16(A + abase[i] + k0, &As[cur ^ 1][tid * 8 + i * 2048]);
                gload16(Bt + bbase[i] + k0, &Bs[cur ^ 1][tid * 8 + i * 2048]);
            }
        }
        f16x8 af[4], bf[4];
#pragma unroll
        for (int f = 0; f < 4; ++f) {
            af[f] = *(const f16x8*)&As[cur][(wm * 64 + f * 16) * 32 + fragoff];
            bf[f] = *(const f16x8*)&Bs[cur][(wn * 64 + f * 16) * 32 + fragoff];
        }
#pragma unroll
        for (int fi = 0; fi < 4; ++fi)
#pragma unroll
            for (int fj = 0; fj < 4; ++fj)
                acc[fi][fj] = __builtin_amdgcn_mfma_f32_16x16x32_f16(
                    af[fi], bf[fj], acc[fi][fj], 0, 0, 0);
        __syncthreads();
        cur ^= 1;
    }
    // D layout: row = (lane>>4)*4 + reg, col = lane&15 (m89-verified)
    if (FUSE) {
        // fused final layer: relu + bias, dot with Wof, 16-lane butterfly,
        // one fp32 atomicAdd per (row, wave, col-block) partial
#pragma unroll
        for (int fi = 0; fi < 4; ++fi)
#pragma unroll
            for (int r = 0; r < 4; ++r) {
                float part = 0.f;
#pragma unroll
                for (int fj = 0; fj < 4; ++fj) {
                    int n = col0 + wn * 64 + fj * 16 + l15;
                    float v = acc[fi][fj][r];
                    if (BIAS) v += biasp[n];
                    if (RELU) v = fmaxf(v, 0.f);
                    part += v * Wof[n];
                }
                part += __shfl_xor(part, 1, 64);
                part += __shfl_xor(part, 2, 64);
                part += __shfl_xor(part, 4, 64);
                part += __shfl_xor(part, 8, 64);
                int row = row0 + wm * 64 + fi * 16 + lk * 4 + r;
                if (l15 == 0 && row < M) atomicAdd(out + row, part);
            }
    } else {
#pragma unroll
        for (int fi = 0; fi < 4; ++fi)
#pragma unroll
            for (int r = 0; r < 4; ++r) {
                int row = row0 + wm * 64 + fi * 16 + lk * 4 + r;
                if (row < M) {
#pragma unroll
                    for (int fj = 0; fj < 4; ++fj) {
                        int n = col0 + wn * 64 + fj * 16 + l15;
                        float v = acc[fi][fj][r];
                        if (BIAS) v += biasp[n];
                        if (RELU) v = fmaxf(v, 0.f);
                        C[(size_t)row * Npad + n] = (f16)v;
                    }
                }
            }
    }
}

extern "C" void kernel_launch(void* const* d_in, const int* in_sizes, int n_in,
                              void* d_out, int out_size, void* d_ws, size_t ws_size,
                              hipStream_t stream) {
    const float* x      = (const float*)d_in[0];
    const void*  ei     = d_in[1];
    const float* conv_W = (const float*)d_in[2];
    const float* conv_b = (const float*)d_in[3];
    const float* W1 = (const float*)d_in[4];
    const float* b1 = (const float*)d_in[5];
    const float* W2 = (const float*)d_in[6];
    const float* b2 = (const float*)d_in[7];
    const float* W3 = (const float*)d_in[8];
    const float* b3 = (const float*)d_in[9];
    const float* Wo = (const float*)d_in[10];
    const float* bo = (const float*)d_in[11];
    float* out = (float*)d_out;

    char* ws = (char*)d_ws;
    size_t off_b = 0;
    auto alloc = [&](size_t bytes) {
        void* p = ws + off_b;
        off_b = (off_b + bytes + 255) & ~(size_t)255;
        return p;
    };
    f16*   xh   = (f16*)alloc((size_t)NN * 128 * 2);
    f16*   xwh  = (f16*)alloc((size_t)NN * 128 * 2);
    f16*   h0h  = (f16*)alloc((size_t)NN * 128 * 2);
    f16*   h1h  = (f16*)alloc((size_t)NN * 512 * 2);
    f16*   h2h  = (f16*)alloc((size_t)NN * 512 * 2);
    f16*   cWT  = (f16*)alloc(128 * 128 * 2);
    f16*   W1T  = (f16*)alloc(512 * 128 * 2);
    f16*   W2T  = (f16*)alloc(512 * 512 * 2);
    f16*   W3T  = (f16*)alloc(512 * 512 * 2);
    float* Wof  = (float*)alloc(512 * 4);
    float* b1p  = (float*)alloc(512 * 4);
    float* b2p  = (float*)alloc(512 * 4);
    float* b3p  = (float*)alloc(512 * 4);
    int*   degi   = (int*)alloc(NN * 4);
    int*   offn   = (int*)alloc(NN * 4);
    int*   cursor = (int*)alloc(NN * 4);
    float* dinv   = (float*)alloc(NN * 4);
    int*   bsum   = (int*)alloc(NBLK * 4);
    int*   boff   = (int*)alloc(NBLK * 4);
    int*   csr    = (int*)alloc((size_t)NE * 4);

    hipMemsetAsync(degi, 0, (size_t)NN * 4, stream);
    hipMemsetAsync(cursor, 0, (size_t)NN * 4, stream);

    prep_all<<<(1408256 + 255) / 256, 256, 0, stream>>>(
        x, xh, conv_W, W1, W2, W3, Wo, b1, b2, b3,
        cWT, W1T, W2T, W3T, Wof, b1p, b2p, b3p);

    // xw = x @ conv_W   (fp16 out)
    mfma_gemm<false, false, false, false><<<dim3(1, 391), 256, 0, stream>>>(
        xh, cWT, nullptr, xwh, nullptr, nullptr, NN, 128, 128);

    deg_kernel<<<(NE + 255) / 256, 256, 0, stream>>>(ei, degi);
    scan_blocksum<<<NBLK, 1024, 0, stream>>>(degi, bsum);
    scan_top<<<1, 64, 0, stream>>>(bsum, boff);
    scan_apply<<<NBLK, 1024, 0, stream>>>(degi, boff, offn, dinv, bo, out);
    fill_kernel<<<(NE + 255) / 256, 256, 0, stream>>>(ei, offn, cursor, csr);
    gather_kernel<<<(NN + 3) / 4, 256, 0, stream>>>(csr, offn, degi, xwh, dinv, conv_b, h0h);

    // h1 = relu(h0 @ W1 + b1)
    mfma_gemm<true, true, true, false><<<dim3(4, 392), 256, 0, stream>>>(
        h0h, W1T, b1p, h1h, nullptr, nullptr, NN, 512, 128);
    // h2 = relu(h1 @ W2 + b2)
    mfma_gemm<true, true, true, false><<<dim3(4, 392), 256, 0, stream>>>(
        h1h, W2T, b2p, h2h, nullptr, nullptr, NN, 512, 512);
    // out += relu(h2 @ W3 + b3) @ Wo   (h3 never materialized; out pre-init to bo)
    mfma_gemm<true, true, true, true><<<dim3(4, 392), 256, 0, stream>>>(
        h2h, W3T, b3p, nullptr, Wof, out, NN, 512, 512);
}

// Round 7
// 353.896 us; speedup vs baseline: 8.6408x; 1.0601x over previous
//
#include <hip/hip_runtime.h>
#include <hip/hip_bf16.h>
#include <hip/hip_fp16.h>

#define NN 50000
#define NE 800000

typedef _Float16 f16;
typedef _Float16 f16x2 __attribute__((ext_vector_type(2)));
typedef _Float16 f16x8 __attribute__((ext_vector_type(8)));
typedef float f32x4 __attribute__((ext_vector_type(4)));

// ---------- async global->LDS 16B ----------
__device__ __forceinline__ void gload16(const f16* g, f16* l) {
    __builtin_amdgcn_global_load_lds(
        (__attribute__((address_space(1))) void*)(void*)g,
        (__attribute__((address_space(3))) void*)(void*)l, 16, 0, 0);
}

// ---------- inline edge dtype detection (int32 vs int64) ----------
__device__ __forceinline__ int detect_mode(const void* ei) {
    const long long* p = (const long long*)ei;
    int ok = 1;
#pragma unroll
    for (int i = 0; i < 8; ++i) {
        long long v = p[i];
        if (v < 0 || v >= NN) ok = 0;
    }
    return ok;
}

__device__ __forceinline__ int edge_at(const void* ei, int mode, int idx) {
    if (mode) return (int)((const long long*)ei)[idx];
    return ((const int*)ei)[idx];
}

// ---------- scan phase 1: per-1024-chunk sums ----------
#define NBLK 49
__global__ __launch_bounds__(1024)
void scan_blocksum(const int* __restrict__ degi, int* __restrict__ bsum) {
    __shared__ int red[1024];
    int i = blockIdx.x * 1024 + threadIdx.x;
    red[threadIdx.x] = (i < NN) ? degi[i] : 0;
    __syncthreads();
    for (int s = 512; s > 0; s >>= 1) {
        if (threadIdx.x < s) red[threadIdx.x] += red[threadIdx.x + s];
        __syncthreads();
    }
    if (threadIdx.x == 0) bsum[blockIdx.x] = red[0];
}

// ---------- scan phase 2: intra-chunk scan + inline top-level prefix;
// also dinv = rsqrt(deg+1) and out pre-init to bo ----------
__global__ __launch_bounds__(1024)
void scan_apply(const int* __restrict__ degi, const int* __restrict__ bsum,
                int* __restrict__ off, float* __restrict__ dinv,
                const float* __restrict__ bo, float* __restrict__ out) {
    __shared__ int tmp[1024];
    __shared__ int base;
    int tid = threadIdx.x;
    if (tid == 0) {
        int a = 0;
        for (int b = 0; b < (int)blockIdx.x; ++b) a += bsum[b];
        base = a;
    }
    int i = blockIdx.x * 1024 + tid;
    int v = (i < NN) ? degi[i] : 0;
    tmp[tid] = v;
    __syncthreads();
    for (int s = 1; s < 1024; s <<= 1) {
        int t = (tid >= s) ? tmp[tid - s] : 0;
        __syncthreads();
        tmp[tid] += t;
        __syncthreads();
    }
    if (i < NN) {
        off[i] = base + tmp[tid] - v;               // exclusive
        dinv[i] = rsqrtf((float)v + 1.0f);          // +1 self loop
        out[i] = bo[0];
    }
}

// ---------- CSR fill ----------
__global__ void fill_kernel(const void* ei,
                            const int* __restrict__ off, int* __restrict__ cursor,
                            int* __restrict__ csr) {
    int e = blockIdx.x * blockDim.x + threadIdx.x;
    if (e >= NE) return;
    int mode = detect_mode(ei);
    int s = edge_at(ei, mode, e);
    int d = edge_at(ei, mode, NE + e);
    int pos = atomicAdd(&cursor[d], 1);
    csr[off[d] + pos] = s;
}

// ---------- gather (fp16 xw -> fp16 h0, fused self-loop+bias+relu) ----------
__global__ __launch_bounds__(256)
void gather_kernel(const int* __restrict__ csr, const int* __restrict__ off,
                   const int* __restrict__ degi, const f16* __restrict__ xwh,
                   const float* __restrict__ dinv, const float* __restrict__ conv_b,
                   f16* __restrict__ h0h) {
    int wv = threadIdx.x >> 6, lane = threadIdx.x & 63;
    int n = blockIdx.x * 4 + wv;
    if (n >= NN) return;
    int o = off[n], dg = degi[n];
    float ax = 0.f, ay = 0.f, bx = 0.f, by = 0.f;
    int j = 0;
    for (; j + 1 < dg; j += 2) {
        int s0 = csr[o + j], s1 = csr[o + j + 1];
        float d0 = dinv[s0], d1 = dinv[s1];
        f16x2 v0 = *(const f16x2*)(xwh + (size_t)s0 * 128 + lane * 2);
        f16x2 v1 = *(const f16x2*)(xwh + (size_t)s1 * 128 + lane * 2);
        ax += (float)v0[0] * d0; ay += (float)v0[1] * d0;
        bx += (float)v1[0] * d1; by += (float)v1[1] * d1;
    }
    if (j < dg) {
        int s0 = csr[o + j];
        float d0 = dinv[s0];
        f16x2 v0 = *(const f16x2*)(xwh + (size_t)s0 * 128 + lane * 2);
        ax += (float)v0[0] * d0; ay += (float)v0[1] * d0;
    }
    float dn = dinv[n];
    f16x2 vs = *(const f16x2*)(xwh + (size_t)n * 128 + lane * 2);
    float rx = (ax + bx + (float)vs[0] * dn) * dn + conv_b[lane * 2];
    float ry = (ay + by + (float)vs[1] * dn) * dn + conv_b[lane * 2 + 1];
    f16x2 r;
    r[0] = (f16)fmaxf(rx, 0.f);
    r[1] = (f16)fmaxf(ry, 0.f);
    *(f16x2*)(h0h + (size_t)n * 128 + lane * 2) = r;
}

// ---------- merged prep: x->fp16, weights transpose/pad, degree histogram ----------
__global__ void prep_all(const float* __restrict__ x, f16* __restrict__ xh,
                         const float* __restrict__ cW, const float* __restrict__ W1,
                         const float* __restrict__ W2, const float* __restrict__ W3,
                         const float* __restrict__ Wo, const float* __restrict__ b1,
                         const float* __restrict__ b2, const float* __restrict__ b3,
                         f16* __restrict__ cWT, f16* __restrict__ W1T,
                         f16* __restrict__ W2T, f16* __restrict__ W3T,
                         float* __restrict__ Wof, float* __restrict__ b1p,
                         float* __restrict__ b2p, float* __restrict__ b3p,
                         const void* ei, int* __restrict__ degi) {
    int i = blockIdx.x * 256 + threadIdx.x;
    if (i < 800000) {               // convert x, 8 elems/thread
        int e = i * 8;
        float4 u0 = *(const float4*)(x + e);
        float4 u1 = *(const float4*)(x + e + 4);
        f16x8 o;
        o[0] = (f16)u0.x; o[1] = (f16)u0.y; o[2] = (f16)u0.z; o[3] = (f16)u0.w;
        o[4] = (f16)u1.x; o[5] = (f16)u1.y; o[6] = (f16)u1.z; o[7] = (f16)u1.w;
        *(f16x8*)(xh + e) = o;
        return;
    }
    i -= 800000;
    if (i < 16384) { int n = i >> 7, k = i & 127; cWT[i] = (f16)cW[k * 128 + n]; return; }
    i -= 16384;
    if (i < 65536) { int n = i >> 7, k = i & 127; W1T[i] = (f16)((n < 500) ? W1[k * 500 + n] : 0.f); return; }
    i -= 65536;
    if (i < 262144) { int n = i >> 9, k = i & 511; W2T[i] = (f16)((n < 500 && k < 500) ? W2[k * 500 + n] : 0.f); return; }
    i -= 262144;
    if (i < 262144) { int n = i >> 9, k = i & 511; W3T[i] = (f16)((n < 500 && k < 500) ? W3[k * 500 + n] : 0.f); return; }
    i -= 262144;
    if (i < 512) { Wof[i] = (i < 500) ? Wo[i] : 0.f; return; }
    i -= 512;
    if (i < 512) { b1p[i] = (i < 500) ? b1[i] : 0.f; return; }
    i -= 512;
    if (i < 512) { b2p[i] = (i < 500) ? b2[i] : 0.f; return; }
    i -= 512;
    if (i < 512) { b3p[i] = (i < 500) ? b3[i] : 0.f; return; }
    i -= 512;
    if (i < NE) {                   // degree histogram
        int mode = detect_mode(ei);
        int d = edge_at(ei, mode, NE + i);
        atomicAdd(&degi[d], 1);
    }
}

// ---------- MFMA f16 GEMM, counted-vmcnt 3-buffer pipeline ----------
// 128x128 tile, 4 waves (2x2), BK=32. K-tile t+2 staged at iter t; per K-tile:
//   s_barrier(#1: prev readers done with recycled buf) -> issue 4 gload_lds ->
//   s_waitcnt vmcnt(8) (2 newer tiles stay IN FLIGHT) -> s_barrier(#2) -> MFMA.
// Never drains vmcnt to 0 in steady state (T4). Requires nt >= 2.
// SWZ: panel-group block swizzle (4 col-blocks of a row panel -> same XCD).
// FUSE: final layer fused (dot Wof + butterfly + atomicAdd into out).
template <bool SWZ, bool RELU, bool BIAS, bool FUSE>
__global__ __launch_bounds__(256)
void mfma_gemm(const f16* __restrict__ A, const f16* __restrict__ Bt,
               const float* __restrict__ biasp, f16* __restrict__ C,
               const float* __restrict__ Wof, float* __restrict__ out,
               int M, int Npad, int K) {
    int bx, by;
    if (SWZ) {
        int id = blockIdx.x + 4 * blockIdx.y;
        int x = id & 7, s = id >> 3;
        bx = s & 3;
        by = (s >> 2) * 8 + x;
        if (by * 128 >= M) return;   // uniform: padded panel
    } else {
        bx = blockIdx.x; by = blockIdx.y;
    }
    __shared__ f16 As[3][4096];
    __shared__ f16 Bs[3][4096];
    const int tid = threadIdx.x;
    const int lane = tid & 63;
    const int wm = (tid >> 6) >> 1, wn = (tid >> 6) & 1;
    const int l15 = lane & 15, lk = lane >> 4;
    const int row0 = by * 128, col0 = bx * 128;

    // staging: slot s (0..511 per matrix), m/n = s>>2, physical 16B col = s&3,
    // global k-group = (s&3) ^ (m&3)  [involution; read applies same XOR]
    size_t abase[2], bbase[2];
#pragma unroll
    for (int i = 0; i < 2; ++i) {
        int s = tid + i * 256;
        int m = s >> 2;
        int kgp = (s & 3) ^ (m & 3);
        int row = row0 + m; if (row > M - 1) row = M - 1;   // clamp: garbage rows, not stored
        abase[i] = (size_t)row * K + kgp * 8;
        bbase[i] = (size_t)(col0 + m) * K + kgp * 8;
    }
    const int fragoff = l15 * 32 + ((lk ^ (l15 & 3)) * 8);  // halves
    f32x4 acc[4][4] = {};

    const int nt = K >> 5;   // >= 4 for all our calls

#define STAGE(buf, t)                                              \
    {                                                              \
        int _k0 = (t) << 5;                                        \
        _Pragma("unroll")                                          \
        for (int i = 0; i < 2; ++i) {                              \
            gload16(A + abase[i] + _k0, &As[buf][tid * 8 + i * 2048]);  \
            gload16(Bt + bbase[i] + _k0, &Bs[buf][tid * 8 + i * 2048]); \
        }                                                          \
    }

#define COMPUTE(buf)                                               \
    {                                                              \
        f16x8 af[4], bf[4];                                        \
        _Pragma("unroll")                                          \
        for (int f = 0; f < 4; ++f) {                              \
            af[f] = *(const f16x8*)&As[buf][(wm * 64 + f * 16) * 32 + fragoff]; \
            bf[f] = *(const f16x8*)&Bs[buf][(wn * 64 + f * 16) * 32 + fragoff]; \
        }                                                          \
        _Pragma("unroll")                                          \
        for (int fi = 0; fi < 4; ++fi)                             \
            _Pragma("unroll")                                      \
            for (int fj = 0; fj < 4; ++fj)                         \
                acc[fi][fj] = __builtin_amdgcn_mfma_f32_16x16x32_f16( \
                    af[fi], bf[fj], acc[fi][fj], 0, 0, 0);         \
    }

    // prologue: stage K-tiles 0,1 into bufs 0,1 (8 loads in flight)
    STAGE(0, 0);
    STAGE(1, 1);

    int cur = 0;
    for (int t = 0; t < nt - 2; ++t) {
        int pb = cur + 2; if (pb >= 3) pb -= 3;
        __builtin_amdgcn_sched_barrier(0);
        __builtin_amdgcn_s_barrier();          // #1: all waves done reading buf pb
        __builtin_amdgcn_sched_barrier(0);
        STAGE(pb, t + 2);
        asm volatile("s_waitcnt vmcnt(8)" ::: "memory");  // tile t's 4 landed; 8 newer in flight
        __builtin_amdgcn_sched_barrier(0);
        __builtin_amdgcn_s_barrier();          // #2: every wave's tile-t loads landed
        __builtin_amdgcn_sched_barrier(0);
        COMPUTE(cur);
        cur += 1; if (cur >= 3) cur -= 3;
    }
    // tail tile nt-2: nothing to stage; 4 newer (tile nt-1) stay in flight
    {
        __builtin_amdgcn_sched_barrier(0);
        __builtin_amdgcn_s_barrier();
        asm volatile("s_waitcnt vmcnt(4)" ::: "memory");
        __builtin_amdgcn_sched_barrier(0);
        __builtin_amdgcn_s_barrier();
        __builtin_amdgcn_sched_barrier(0);
        COMPUTE(cur);
        cur += 1; if (cur >= 3) cur -= 3;
    }
    // tail tile nt-1: final drain
    {
        __builtin_amdgcn_sched_barrier(0);
        __builtin_amdgcn_s_barrier();
        asm volatile("s_waitcnt vmcnt(0)" ::: "memory");
        __builtin_amdgcn_sched_barrier(0);
        __builtin_amdgcn_s_barrier();
        __builtin_amdgcn_sched_barrier(0);
        COMPUTE(cur);
    }
#undef STAGE
#undef COMPUTE

    // D layout: row = (lane>>4)*4 + reg, col = lane&15 (m89-verified)
    if (FUSE) {
#pragma unroll
        for (int fi = 0; fi < 4; ++fi)
#pragma unroll
            for (int r = 0; r < 4; ++r) {
                float part = 0.f;
#pragma unroll
                for (int fj = 0; fj < 4; ++fj) {
                    int n = col0 + wn * 64 + fj * 16 + l15;
                    float v = acc[fi][fj][r];
                    if (BIAS) v += biasp[n];
                    if (RELU) v = fmaxf(v, 0.f);
                    part += v * Wof[n];
                }
                part += __shfl_xor(part, 1, 64);
                part += __shfl_xor(part, 2, 64);
                part += __shfl_xor(part, 4, 64);
                part += __shfl_xor(part, 8, 64);
                int row = row0 + wm * 64 + fi * 16 + lk * 4 + r;
                if (l15 == 0 && row < M) atomicAdd(out + row, part);
            }
    } else {
#pragma unroll
        for (int fi = 0; fi < 4; ++fi)
#pragma unroll
            for (int r = 0; r < 4; ++r) {
                int row = row0 + wm * 64 + fi * 16 + lk * 4 + r;
                if (row < M) {
#pragma unroll
                    for (int fj = 0; fj < 4; ++fj) {
                        int n = col0 + wn * 64 + fj * 16 + l15;
                        float v = acc[fi][fj][r];
                        if (BIAS) v += biasp[n];
                        if (RELU) v = fmaxf(v, 0.f);
                        C[(size_t)row * Npad + n] = (f16)v;
                    }
                }
            }
    }
}

extern "C" void kernel_launch(void* const* d_in, const int* in_sizes, int n_in,
                              void* d_out, int out_size, void* d_ws, size_t ws_size,
                              hipStream_t stream) {
    const float* x      = (const float*)d_in[0];
    const void*  ei     = d_in[1];
    const float* conv_W = (const float*)d_in[2];
    const float* conv_b = (const float*)d_in[3];
    const float* W1 = (const float*)d_in[4];
    const float* b1 = (const float*)d_in[5];
    const float* W2 = (const float*)d_in[6];
    const float* b2 = (const float*)d_in[7];
    const float* W3 = (const float*)d_in[8];
    const float* b3 = (const float*)d_in[9];
    const float* Wo = (const float*)d_in[10];
    const float* bo = (const float*)d_in[11];
    float* out = (float*)d_out;

    char* ws = (char*)d_ws;
    size_t off_b = 0;
    auto alloc = [&](size_t bytes) {
        void* p = ws + off_b;
        off_b = (off_b + bytes + 255) & ~(size_t)255;
        return p;
    };
    f16*   xh   = (f16*)alloc((size_t)NN * 128 * 2);
    f16*   xwh  = (f16*)alloc((size_t)NN * 128 * 2);
    f16*   h0h  = (f16*)alloc((size_t)NN * 128 * 2);
    f16*   h1h  = (f16*)alloc((size_t)NN * 512 * 2);
    f16*   h2h  = (f16*)alloc((size_t)NN * 512 * 2);
    f16*   cWT  = (f16*)alloc(128 * 128 * 2);
    f16*   W1T  = (f16*)alloc(512 * 128 * 2);
    f16*   W2T  = (f16*)alloc(512 * 512 * 2);
    f16*   W3T  = (f16*)alloc(512 * 512 * 2);
    float* Wof  = (float*)alloc(512 * 4);
    float* b1p  = (float*)alloc(512 * 4);
    float* b2p  = (float*)alloc(512 * 4);
    float* b3p  = (float*)alloc(512 * 4);
    int*   degi   = (int*)alloc(NN * 4);
    int*   offn   = (int*)alloc(NN * 4);
    int*   cursor = (int*)alloc(NN * 4);
    float* dinv   = (float*)alloc(NN * 4);
    int*   bsum   = (int*)alloc(NBLK * 4);
    int*   csr    = (int*)alloc((size_t)NE * 4);

    hipMemsetAsync(degi, 0, (size_t)NN * 4, stream);
    hipMemsetAsync(cursor, 0, (size_t)NN * 4, stream);

    // prep (x convert + weights + degree histogram), 2208256 work items
    prep_all<<<(2208256 + 255) / 256, 256, 0, stream>>>(
        x, xh, conv_W, W1, W2, W3, Wo, b1, b2, b3,
        cWT, W1T, W2T, W3T, Wof, b1p, b2p, b3p, ei, degi);

    // xw = x @ conv_W   (fp16 out)
    mfma_gemm<false, false, false, false><<<dim3(1, 391), 256, 0, stream>>>(
        xh, cWT, nullptr, xwh, nullptr, nullptr, NN, 128, 128);

    scan_blocksum<<<NBLK, 1024, 0, stream>>>(degi, bsum);
    scan_apply<<<NBLK, 1024, 0, stream>>>(degi, bsum, offn, dinv, bo, out);
    fill_kernel<<<(NE + 255) / 256, 256, 0, stream>>>(ei, offn, cursor, csr);
    gather_kernel<<<(NN + 3) / 4, 256, 0, stream>>>(csr, offn, degi, xwh, dinv, conv_b, h0h);

    // h1 = relu(h0 @ W1 + b1)
    mfma_gemm<true, true, true, false><<<dim3(4, 392), 256, 0, stream>>>(
        h0h, W1T, b1p, h1h, nullptr, nullptr, NN, 512, 128);
    // h2 = relu(h1 @ W2 + b2)
    mfma_gemm<true, true, true, false><<<dim3(4, 392), 256, 0, stream>>>(
        h1h, W2T, b2p, h2h, nullptr, nullptr, NN, 512, 512);
    // out += relu(h2 @ W3 + b3) @ Wo   (h3 never materialized; out pre-init to bo)
    mfma_gemm<true, true, true, true><<<dim3(4, 392), 256, 0, stream>>>(
        h2h, W3T, b3p, nullptr, Wof, out, NN, 512, 512);
}